// Round 7
// baseline (8043.183 us; speedup 1.0000x reference)
//
#include <hip/hip_runtime.h>

#define TT 200
#define BB 128
#define CC 171
#define HH 1024

typedef __attribute__((ext_vector_type(8))) short short8;
typedef __attribute__((ext_vector_type(4))) float f32x4;

__device__ __forceinline__ unsigned short f2bf(float f) {
  unsigned int u = __float_as_uint(f);
  u += 0x7fff + ((u >> 16) & 1);   // RNE
  return (unsigned short)(u >> 16);
}
__device__ __forceinline__ float sigmoidf_(float x) { return 1.f / (1.f + __expf(-x)); }

// coherent (cross-XCD) 16B load: bypass L1+L2, served at Infinity Cache
__device__ __forceinline__ int4 ld_coh16(const void* p) {
  int4 r;
  asm volatile("global_load_dwordx4 %0, %1, off sc0 sc1" : "=v"(r) : "v"(p));
  return r;
}
// coherent 2B store (write-through to IF$)
__device__ __forceinline__ void st_coh2(void* p, unsigned int v) {
  asm volatile("global_store_short %0, %1, off sc0 sc1" :: "v"(p), "v"(v) : "memory");
}
// inline-asm memory ops are NOT tracked by compiler waitcnt insertion
__device__ __forceinline__ void drain_vm() {
  asm volatile("s_waitcnt vmcnt(0)" ::: "memory");
}

// ---- two-level grid barrier, monotonic epochs ----
// layout (ints): grp cnt g at [g*32] (0..224); grp gen g at [(16+g)*32] (512..736);
// master cnt at [960]. DISJOINT — round 6 had gen0 colliding with master cnt.
__device__ __forceinline__ void gridbar(int* bar, int wg, int tid, int epoch) {
  drain_vm();
  __syncthreads();
  if (tid == 0) {
    int g = wg & 7;
    int o = __hip_atomic_fetch_add(&bar[g * 32], 1, __ATOMIC_RELAXED, __HIP_MEMORY_SCOPE_AGENT);
    if (o == epoch * 32 - 1) {
      int m = __hip_atomic_fetch_add(&bar[960], 1, __ATOMIC_RELAXED, __HIP_MEMORY_SCOPE_AGENT);
      if (m == epoch * 8 - 1) {
#pragma unroll
        for (int i = 0; i < 8; ++i)
          __hip_atomic_store(&bar[(16 + i) * 32], epoch, __ATOMIC_RELAXED, __HIP_MEMORY_SCOPE_AGENT);
      }
    }
    while (__hip_atomic_load(&bar[(16 + g) * 32], __ATOMIC_RELAXED, __HIP_MEMORY_SCOPE_AGENT) < epoch)
      __builtin_amdgcn_s_sleep(1);
  }
  asm volatile("" ::: "memory");
  __syncthreads();
}

// ---------------- fused GEMM + LSTM cell phase ----------------
// 16 waves = 4 K-groups x 4 gate-waves, tile M32 x N64 (gate-permuted).
// A: coherent loads -> LDS (one barrier). B: direct L2-cached loads, dual source
// (Wa for kt<NKT1, Wb after). A1 is bf16 (stride sA1) or f32 seq (A1SEQ).
template<int NKT1, int NKTTOT, bool A1SEQ>
__device__ __forceinline__ void lstm_phase(
    const void* A1v, int sA1,
    const unsigned short* __restrict__ A2, int sA2,
    const unsigned short* __restrict__ Wa, int sWa,
    const unsigned short* __restrict__ Wb, int sWb,
    const float* __restrict__ bias,
    float& creg, unsigned short* __restrict__ Hout,
    char* smem, int m0, int n0, int ntile, int tid)
{
  constexpr int BASE = NKTTOT / 4;
  constexpr int REM = NKTTOT % 4;
  constexpr int MAXKT = BASE + (REM ? 1 : 0);

  const int wave = tid >> 6, lane = tid & 63;
  const int grp = wave >> 2, gw = wave & 3;
  const int lrow = lane >> 3, lj = lane & 7;
  const int fl = lane & 15, fh = lane >> 4;

  const int kt0 = grp * BASE + min(grp, REM);
  const int ktn = BASE + (grp < REM ? 1 : 0);

  // ---- bulk A staging ----
  char* Ar = smem + grp * 32768;
  const int row = gw * 8 + lrow;
  int4 areg[MAXKT];
#pragma unroll
  for (int i = 0; i < MAXKT; ++i) {
    if (i < ktn) {
      int kt = kt0 + i;
      if (kt < NKT1) {
        if constexpr (A1SEQ) {
          const float* srow = (const float*)A1v + (size_t)(m0 + row) * sA1;
          int c0 = kt * 64 + ((lj ^ (row & 7)) << 3);
          unsigned int w[4];
#pragma unroll
          for (int j = 0; j < 4; ++j) {
            int ca = c0 + 2 * j, cb = c0 + 2 * j + 1;
            float va = (ca < CC) ? srow[ca] : 0.f;
            float vb = (cb < CC) ? srow[cb] : 0.f;
            w[j] = (unsigned int)f2bf(va) | ((unsigned int)f2bf(vb) << 16);
          }
          areg[i] = make_int4(w[0], w[1], w[2], w[3]);
        } else {
          const unsigned short* srow = (const unsigned short*)A1v + (size_t)(m0 + row) * sA1;
          areg[i] = ld_coh16(srow + kt * 64 + ((lj ^ (row & 7)) << 3));
        }
      } else {
        areg[i] = ld_coh16(A2 + (size_t)(m0 + row) * sA2 + (kt - NKT1) * 64 + ((lj ^ (row & 7)) << 3));
      }
    }
  }
  drain_vm();   // untracked inline-asm loads: wait before consuming areg[]
#pragma unroll
  for (int i = 0; i < MAXKT; ++i)
    if (i < ktn) *(int4*)(Ar + i * 4096 + row * 128 + lj * 16) = areg[i];
  __syncthreads();

  // ---- barrier-free inner loop: B direct from L2, A from LDS ----
  f32x4 acc0 = {0.f, 0.f, 0.f, 0.f}, acc1 = {0.f, 0.f, 0.f, 0.f};
  const int wrowi = n0 + gw * 16 + fl;
  const int swz = (fl & 7) << 4;
#pragma unroll
  for (int i = 0; i < MAXKT; ++i) {
    if (i < ktn) {
      int kt = kt0 + i;
      const unsigned short* wr = (kt < NKT1)
          ? Wa + (size_t)wrowi * sWa + kt * 64 + fh * 8
          : Wb + (size_t)wrowi * sWb + (kt - NKT1) * 64 + fh * 8;
#pragma unroll
      for (int kk = 0; kk < 2; ++kk) {
        short8 b0 = *(const short8*)(wr + kk * 32);
        int colb = kk * 64 + fh * 16;
        short8 a0 = *(const short8*)(Ar + i * 4096 + fl * 128 + (colb ^ swz));
        short8 a1 = *(const short8*)(Ar + i * 4096 + (16 + fl) * 128 + (colb ^ swz));
        acc0 = __builtin_amdgcn_mfma_f32_16x16x32_bf16(a0, b0, acc0, 0, 0, 0);
        acc1 = __builtin_amdgcn_mfma_f32_16x16x32_bf16(a1, b0, acc1, 0, 0, 0);
      }
    }
  }

  // ---- K-partial exchange + cell update (C in registers) ----
  __syncthreads();
  float* ex = (float*)smem;
#pragma unroll
  for (int r = 0; r < 4; ++r) {
    ex[((grp * 4 + gw) * 32 + fh * 4 + r) * 16 + fl] = acc0[r];
    ex[((grp * 4 + gw) * 32 + 16 + fh * 4 + r) * 16 + fl] = acc1[r];
  }
  __syncthreads();
  if (tid < 512) {
    int urow = tid >> 4, uu = tid & 15;
    float g4[4];
#pragma unroll
    for (int gg = 0; gg < 4; ++gg) {
      float s = ex[(gg * 32 + urow) * 16 + uu] + ex[((4 + gg) * 32 + urow) * 16 + uu]
              + ex[((8 + gg) * 32 + urow) * 16 + uu] + ex[((12 + gg) * 32 + urow) * 16 + uu];
      g4[gg] = s + bias[n0 + gg * 16 + uu];
    }
    float cn = sigmoidf_(g4[1]) * creg + sigmoidf_(g4[0]) * tanhf(g4[2]);
    creg = cn;
    st_coh2(Hout + (size_t)(m0 + urow) * HH + ntile * 16 + uu,
            (unsigned int)f2bf(sigmoidf_(g4[3]) * tanhf(cn)));
  }
}

// ---------------- decoder OUT-only job (straggler, off critical path) ----------
// d in [0,44): tile 32 rows x 16 cols of out[:, t, :]. 16-way K-split.
__device__ __forceinline__ void dec_out(
    const unsigned short* __restrict__ H3in, const unsigned short* __restrict__ Wd,
    const float* __restrict__ bd, float* __restrict__ out,
    int t, char* smem, int d, int tid)
{
  const int wave = tid >> 6, lane = tid & 63;
  const int lrow = lane >> 3, lj = lane & 7;
  const int fl = lane & 15, fh = lane >> 4;
  const int ntile = d % 11, mtile = d / 11;
  const int m0 = mtile * 32, n0 = ntile * 16;

  char* Dr = smem + 65536 + wave * 4096;     // wave-private
  int4 r4[4];
#pragma unroll
  for (int j = 0; j < 4; ++j) {
    int row = j * 8 + lrow;
    r4[j] = ld_coh16(H3in + (size_t)(m0 + row) * HH + wave * 64 + ((lj ^ (row & 7)) << 3));
  }
  drain_vm();
#pragma unroll
  for (int j = 0; j < 4; ++j) {
    int row = j * 8 + lrow;
    *(int4*)(Dr + row * 128 + lj * 16) = r4[j];
  }

  f32x4 acc0 = {0.f, 0.f, 0.f, 0.f}, acc1 = {0.f, 0.f, 0.f, 0.f};
  const unsigned short* Wrow = Wd + (size_t)(n0 + fl) * HH + wave * 64 + fh * 8;
  const int swz = (fl & 7) << 4;
#pragma unroll
  for (int kk = 0; kk < 2; ++kk) {
    short8 b0 = *(const short8*)(Wrow + kk * 32);
    int colb = kk * 64 + fh * 16;
    short8 a0 = *(const short8*)(Dr + fl * 128 + (colb ^ swz));
    short8 a1 = *(const short8*)(Dr + (16 + fl) * 128 + (colb ^ swz));
    acc0 = __builtin_amdgcn_mfma_f32_16x16x32_bf16(a0, b0, acc0, 0, 0, 0);
    acc1 = __builtin_amdgcn_mfma_f32_16x16x32_bf16(a1, b0, acc1, 0, 0, 0);
  }

  float* pex = (float*)(smem + 32768);       // disjoint from lstm ex (0..32K) and Dr (64K+)
#pragma unroll
  for (int r = 0; r < 4; ++r) {
    pex[(wave * 32 + fh * 4 + r) * 16 + fl] = acc0[r];
    pex[(wave * 32 + 16 + fh * 4 + r) * 16 + fl] = acc1[r];
  }
  __syncthreads();
  if (tid < 512) {
    int row = tid >> 4, uu = tid & 15;
    int c = n0 + uu;
    if (c < CC) {
      float s = 0.f;
#pragma unroll
      for (int v = 0; v < 16; ++v) s += pex[(v * 32 + row) * 16 + uu];
      out[(size_t)(m0 + row) * (TT * CC) + (size_t)t * CC + c] = s + bd[c];
    }
  }
}

// ---------------- persistent megakernel ----------------
__global__ __launch_bounds__(1024, 1) void persistent_lstm(
    const unsigned short* __restrict__ Wih1p, const unsigned short* __restrict__ Whh1,
    const unsigned short* __restrict__ Wf, const unsigned short* __restrict__ W2,
    const unsigned short* __restrict__ W3, const unsigned short* __restrict__ Wd,
    const float* __restrict__ B1gt, const float* __restrict__ B1sc,
    const float* __restrict__ B2, const float* __restrict__ B3, const float* __restrict__ Bd,
    unsigned short* __restrict__ Hb, const float* __restrict__ seq, float* __restrict__ out,
    const int* __restrict__ gtp, const int* __restrict__ condp, int* __restrict__ bar)
{
  __shared__ char smem[131072];
  const int wg = blockIdx.x, tid = threadIdx.x;
  const int xg = wg & 7, sl = wg >> 3;
  const int ntile = xg * 8 + (sl >> 2);
  const int m0 = (sl & 3) * 32;
  const int n0 = ntile * 64;
  const int gt = *gtp, cond = *condp;
  const int per = gt + cond;

  int decid = -1;                            // ~6 straggler WGs per XCD
  if (sl >= 26) { int d = xg * 6 + (sl - 26); if (d < 44) decid = d; }

  unsigned short* H1[2] = { Hb + 0 * BB * HH, Hb + 1 * BB * HH };
  unsigned short* H2[2] = { Hb + 2 * BB * HH, Hb + 3 * BB * HH };
  unsigned short* H3[2] = { Hb + 4 * BB * HH, Hb + 5 * BB * HH };

  float c1 = 0.f, c2 = 0.f, c3 = 0.f;
  int e = 0, tm = 0;
  for (int t = 0; t < TT; ++t) {
    int p = t & 1;
    bool gts = (per > 0) ? (tm < gt) : true;
    if (gts)
      lstm_phase<3, 19, true>(seq + (size_t)t * CC, TT * CC, H1[p], HH,
                              Wih1p, 192, Whh1, HH, B1gt, c1, H1[1 - p], smem, m0, n0, ntile, tid);
    else
      lstm_phase<16, 32, false>(H3[p], HH, H1[p], HH,
                                Wf, HH, Whh1, HH, B1sc, c1, H1[1 - p], smem, m0, n0, ntile, tid);
    if (t > 0 && decid >= 0) dec_out(H3[p], Wd, Bd, out, t - 1, smem, decid, tid);
    gridbar(bar, wg, tid, ++e);
    lstm_phase<16, 32, false>(H1[1 - p], HH, H2[p], HH,
                              W2, 2048, W2 + 1024, 2048, B2, c2, H2[1 - p], smem, m0, n0, ntile, tid);
    gridbar(bar, wg, tid, ++e);
    lstm_phase<16, 32, false>(H2[1 - p], HH, H3[p], HH,
                              W3, 2048, W3 + 1024, 2048, B3, c3, H3[1 - p], smem, m0, n0, ntile, tid);
    gridbar(bar, wg, tid, ++e);
    if (++tm == per) tm = 0;
  }
  if (decid >= 0) dec_out(H3[0], Wd, Bd, out, TT - 1, smem, decid, tid);  // h3(199) is in H3[0]
}

// ---------------- conversion / init kernels ----------------
__device__ __forceinline__ int perm_orig_row(int np) {
  return ((np >> 4) & 3) * HH + ((np >> 6) << 4) + (np & 15);
}

__global__ void conv_wih1p(const float* __restrict__ Wih, unsigned short* __restrict__ dst) {
  int np = blockIdx.x, k = threadIdx.x;          // block 192
  int n = perm_orig_row(np);
  dst[(size_t)np * 192 + k] = f2bf((k < CC) ? Wih[(size_t)n * CC + k] : 0.f);
}

__global__ void conv_whh1(const float* __restrict__ Whh, unsigned short* __restrict__ dst) {
  int np = blockIdx.y, k = blockIdx.x * 256 + threadIdx.x;   // grid (4, 4096)
  int n = perm_orig_row(np);
  dst[(size_t)np * HH + k] = f2bf(Whh[(size_t)n * HH + k]);
}

__global__ void conv_w23(const float* __restrict__ Wih, const float* __restrict__ Whh,
                         unsigned short* __restrict__ dst) {
  int k = blockIdx.x * 256 + threadIdx.x;        // grid (8, 4096)
  int np = blockIdx.y;
  int n = perm_orig_row(np);
  float v = (k < HH) ? Wih[(size_t)n * HH + k] : Whh[(size_t)n * HH + (k - HH)];
  dst[(size_t)np * 2048 + k] = f2bf(v);
}

__global__ void conv_wd(const float* __restrict__ Wsrc, unsigned short* __restrict__ dst) {
  int k = blockIdx.x * 256 + threadIdx.x;        // grid (4, 176)
  int row = blockIdx.y;
  dst[(size_t)row * HH + k] = f2bf((row < CC) ? Wsrc[(size_t)row * HH + k] : 0.f);
}

// Wf[np][j] = sum_c W_ih1[n][c] * W_dec[c][j]
__global__ void wf_gemm(const float* __restrict__ Wih1, const float* __restrict__ Wdec,
                        unsigned short* __restrict__ Wfo) {
  int j = blockIdx.x * 256 + threadIdx.x;        // grid (4, 4096)
  int np = blockIdx.y;
  int n = perm_orig_row(np);
  const float* wr = Wih1 + (size_t)n * CC;
  float acc = 0.f;
  for (int c = 0; c < CC; ++c) acc = fmaf(wr[c], Wdec[(size_t)c * HH + j], acc);
  Wfo[(size_t)np * HH + j] = f2bf(acc);
}

__global__ void bias_all(const float* bi1, const float* bh1, const float* Wih1, const float* bdec,
                         const float* bi2, const float* bh2, const float* bi3, const float* bh3,
                         float* o1gt, float* o1sc, float* o2, float* o3, float* od) {
  int idx = blockIdx.x * 256 + threadIdx.x;
  if (idx < 4096) {
    int n = perm_orig_row(idx);
    float b = bi1[n] + bh1[n];
    o1gt[idx] = b;
    const float* wr = Wih1 + (size_t)n * CC;
    float acc = 0.f;
    for (int c = 0; c < CC; ++c) acc = fmaf(wr[c], bdec[c], acc);
    o1sc[idx] = b + acc;
  } else if (idx < 8192) {
    int np = idx - 4096; int n = perm_orig_row(np);
    o2[np] = bi2[n] + bh2[n];
  } else if (idx < 12288) {
    int np = idx - 8192; int n = perm_orig_row(np);
    o3[np] = bi3[n] + bh3[n];
  } else if (idx < 12464) {
    int c2 = idx - 12288;
    od[c2] = (c2 < CC) ? bdec[c2] : 0.f;
  }
}

__global__ void init_state(unsigned short* __restrict__ Hall, int* __restrict__ bar) {
  int idx = blockIdx.x * blockDim.x + threadIdx.x;   // grid 3072 x 256
  if (idx < 6 * BB * HH) Hall[idx] = 0;
  if (idx < 1024) bar[idx] = 0;
}

extern "C" void kernel_launch(void* const* d_in, const int* in_sizes, int n_in,
                              void* d_out, int out_size, void* d_ws, size_t ws_size,
                              hipStream_t stream)
{
  const float* seq   = (const float*)d_in[0];
  const float* W_ih1 = (const float*)d_in[1];
  const float* W_hh1 = (const float*)d_in[2];
  const float* b_ih1 = (const float*)d_in[3];
  const float* b_hh1 = (const float*)d_in[4];
  const float* W_ih2 = (const float*)d_in[5];
  const float* W_hh2 = (const float*)d_in[6];
  const float* b_ih2 = (const float*)d_in[7];
  const float* b_hh2 = (const float*)d_in[8];
  const float* W_ih3 = (const float*)d_in[9];
  const float* W_hh3 = (const float*)d_in[10];
  const float* b_ih3 = (const float*)d_in[11];
  const float* b_hh3 = (const float*)d_in[12];
  const float* W_dec = (const float*)d_in[13];
  const float* b_dec = (const float*)d_in[14];
  const int* condp   = (const int*)d_in[15];
  const int* gtp     = (const int*)d_in[16];
  float* out = (float*)d_out;
  char* ws = (char*)d_ws;

  if (ws_size < 53908480) return;

  unsigned short* Wih1p = (unsigned short*)(ws + 0);
  unsigned short* Whh1  = (unsigned short*)(ws + 1572864);
  unsigned short* Wf    = (unsigned short*)(ws + 9961472);
  unsigned short* W2    = (unsigned short*)(ws + 18350080);
  unsigned short* W3    = (unsigned short*)(ws + 35127296);
  unsigned short* Wd    = (unsigned short*)(ws + 51904512);
  float* B1gt = (float*)(ws + 52264960);
  float* B1sc = (float*)(ws + 52281344);
  float* B2   = (float*)(ws + 52297728);
  float* B3   = (float*)(ws + 52314112);
  float* Bd   = (float*)(ws + 52330496);
  unsigned short* Hbase = (unsigned short*)(ws + 52331520);
  int* bar = (int*)(ws + 53904384);

  conv_wih1p<<<dim3(4096),    192, 0, stream>>>(W_ih1, Wih1p);
  conv_whh1 <<<dim3(4, 4096), 256, 0, stream>>>(W_hh1, Whh1);
  wf_gemm   <<<dim3(4, 4096), 256, 0, stream>>>(W_ih1, W_dec, Wf);
  conv_w23  <<<dim3(8, 4096), 256, 0, stream>>>(W_ih2, W_hh2, W2);
  conv_w23  <<<dim3(8, 4096), 256, 0, stream>>>(W_ih3, W_hh3, W3);
  conv_wd   <<<dim3(4, 176),  256, 0, stream>>>(W_dec, Wd);
  bias_all  <<<dim3(49),      256, 0, stream>>>(b_ih1, b_hh1, W_ih1, b_dec,
                                                b_ih2, b_hh2, b_ih3, b_hh3,
                                                B1gt, B1sc, B2, B3, Bd);
  init_state<<<dim3(3072),    256, 0, stream>>>(Hbase, bar);

  persistent_lstm<<<dim3(256), dim3(1024), 0, stream>>>(
      Wih1p, Whh1, Wf, W2, W3, Wd, B1gt, B1sc, B2, B3, Bd,
      Hbase, seq, out, gtp, condp, bar);
}

// Round 8
// 7138.950 us; speedup vs baseline: 1.1267x; 1.1267x over previous
//
#include <hip/hip_runtime.h>

#define TT 200
#define BB 128
#define CC 171
#define HH 1024

typedef __attribute__((ext_vector_type(8))) short short8;
typedef __attribute__((ext_vector_type(4))) float f32x4;

__device__ __forceinline__ unsigned short f2bf(float f) {
  unsigned int u = __float_as_uint(f);
  u += 0x7fff + ((u >> 16) & 1);   // RNE
  return (unsigned short)(u >> 16);
}
__device__ __forceinline__ float sigmoidf_(float x) { return 1.f / (1.f + __expf(-x)); }

// coherent (cross-XCD) 16B load: bypass L1+L2, served at Infinity Cache
__device__ __forceinline__ int4 ld_coh16(const void* p) {
  int4 r;
  asm volatile("global_load_dwordx4 %0, %1, off sc0 sc1" : "=v"(r) : "v"(p));
  return r;
}
// coherent 2B store (write-through to IF$)
__device__ __forceinline__ void st_coh2(void* p, unsigned int v) {
  asm volatile("global_store_short %0, %1, off sc0 sc1" :: "v"(p), "v"(v) : "memory");
}
__device__ __forceinline__ void drain_vm() {           // wait ALL vm ops
  asm volatile("s_waitcnt vmcnt(0)" ::: "memory");
}
__device__ __forceinline__ void wait4() {              // leave newest 4 loads in flight
  asm volatile("s_waitcnt vmcnt(4)" ::: "memory");
}
// WG barrier guaranteeing only LDS-write visibility (no vmcnt drain!)
__device__ __forceinline__ void bar_lds() {
  asm volatile("s_waitcnt lgkmcnt(0)" ::: "memory");
  __builtin_amdgcn_s_barrier();
  asm volatile("" ::: "memory");
}

// ---- per-m-group barrier: 64 WGs, single counter + gen flag ----
__device__ __forceinline__ void groupbar(int* B, int tid, int epoch) {
  __builtin_amdgcn_s_barrier();          // entry: every wave already drained its stores (wait4/drain)
  if (tid == 0) {
    if (__hip_atomic_fetch_add(&B[0], 1, __ATOMIC_RELAXED, __HIP_MEMORY_SCOPE_AGENT) == epoch * 64 - 1)
      __hip_atomic_store(&B[32], epoch, __ATOMIC_RELAXED, __HIP_MEMORY_SCOPE_AGENT);
    while (__hip_atomic_load(&B[32], __ATOMIC_RELAXED, __HIP_MEMORY_SCOPE_AGENT) < epoch)
      __builtin_amdgcn_s_sleep(1);
  }
  asm volatile("" ::: "memory");
  __builtin_amdgcn_s_barrier();
  asm volatile("" ::: "memory");
}

struct Pre4 { int4 v[4]; };
struct Pre5 { int4 v[5]; };

// prefetch old-half (stable h(t-1)) for a split phase: 4 tiles, cols (grp*4+j)*64
__device__ __forceinline__ void prefetch_old(const unsigned short* A2, int sA2,
    int m0, int grp, int row, int lj, Pre4& P) {
  const unsigned short* base = A2 + (size_t)(m0 + row) * sA2 + ((lj ^ (row & 7)) << 3);
#pragma unroll
  for (int j = 0; j < 4; ++j)
    P.v[j] = ld_coh16(base + (grp * 4 + j) * 64);
}

// prefetch ALL of gt-L1's A (seq f32->bf16 + old h1); ends fully drained
__device__ __forceinline__ void prefetch_gtl1(const float* seqt,
    const unsigned short* H1old, int m0, int grp, int row, int lj, Pre5& P) {
  const int kt0 = grp * 5;                       // grp*4 + min(grp,3), grp<=3
  const int ktn = 4 + (grp < 3 ? 1 : 0);
  const float* srow = seqt + (size_t)(m0 + row) * (TT * CC);
  const unsigned short* hbase = H1old + (size_t)(m0 + row) * HH + ((lj ^ (row & 7)) << 3);
#pragma unroll
  for (int i = 0; i < 5; ++i) {
    if (i < ktn) {
      int kt = kt0 + i;
      if (kt < 3) {                              // seq tiles (grp0 only)
        int c0 = kt * 64 + ((lj ^ (row & 7)) << 3);
        unsigned int w[4];
#pragma unroll
        for (int jj = 0; jj < 4; ++jj) {
          int ca = c0 + 2 * jj, cb = c0 + 2 * jj + 1;
          float va = (ca < CC) ? srow[ca] : 0.f;
          float vb = (cb < CC) ? srow[cb] : 0.f;
          w[jj] = (unsigned int)f2bf(va) | ((unsigned int)f2bf(vb) << 16);
        }
        P.v[i] = make_int4(w[0], w[1], w[2], w[3]);
      } else {
        P.v[i] = ld_coh16(hbase + (kt - 3) * 64);
      }
    }
  }
  drain_vm();                                    // also drains prior stores
}

// shared epilogue: K-partial exchange + LSTM cell + coherent h-store
__device__ __forceinline__ void exchange_cell(f32x4 acc0, f32x4 acc1,
    const float* bias, float& creg, unsigned short* Hout,
    char* smem, int m0, int n0, int ntile, int tid) {
  const int wave = tid >> 6, lane = tid & 63;
  const int grp = wave >> 2, gw = wave & 3;
  const int fl = lane & 15, fh = lane >> 4;
  bar_lds();                                     // all MFMA LDS reads done before ex overwrite
  float* ex = (float*)smem;
#pragma unroll
  for (int r = 0; r < 4; ++r) {
    ex[((grp * 4 + gw) * 32 + fh * 4 + r) * 16 + fl] = acc0[r];
    ex[((grp * 4 + gw) * 32 + 16 + fh * 4 + r) * 16 + fl] = acc1[r];
  }
  bar_lds();
  if (tid < 512) {
    int urow = tid >> 4, uu = tid & 15;
    float g4[4];
#pragma unroll
    for (int gg = 0; gg < 4; ++gg) {
      float s = ex[(gg * 32 + urow) * 16 + uu] + ex[((4 + gg) * 32 + urow) * 16 + uu]
              + ex[((8 + gg) * 32 + urow) * 16 + uu] + ex[((12 + gg) * 32 + urow) * 16 + uu];
      g4[gg] = s + bias[n0 + gg * 16 + uu];
    }
    float cn = sigmoidf_(g4[1]) * creg + sigmoidf_(g4[0]) * tanhf(g4[2]);
    creg = cn;
    st_coh2(Hout + (size_t)(m0 + urow) * HH + ntile * 16 + uu,
            (unsigned int)f2bf(sigmoidf_(g4[3]) * tanhf(cn)));
  }
}

// split phase: 16 new K-tiles (A1, loaded here) + 16 old (prefetched in P).
// grp g: new kt g*4+j (slot j), old kt 16+g*4+j (slot 4+j).
__device__ __forceinline__ void lstm_split(
    const unsigned short* __restrict__ A1, int sA1,
    const unsigned short* __restrict__ Wa, int sWa,   // B rows for new kt, col kt*64
    const unsigned short* __restrict__ Wb, int sWb,   // B rows for old kt, col (kt-16)*64
    const float* __restrict__ bias,
    float& creg, unsigned short* __restrict__ Hout,
    char* smem, int m0, int n0, int ntile, int tid, const Pre4& P)
{
  const int wave = tid >> 6, lane = tid & 63;
  const int grp = wave >> 2, gw = wave & 3;
  const int lrow = lane >> 3, lj = lane & 7;
  const int fl = lane & 15, fh = lane >> 4;
  const int row = gw * 8 + lrow;
  const int swz = (fl & 7) << 4;
  const int wrowi = n0 + gw * 16 + fl;
  char* G = smem + grp * 32768;

  // issue new-half coherent loads immediately (h just published)
  int4 anew[4];
  const unsigned short* nbase = A1 + (size_t)(m0 + row) * sA1 + ((lj ^ (row & 7)) << 3);
#pragma unroll
  for (int j = 0; j < 4; ++j)
    anew[j] = ld_coh16(nbase + (grp * 4 + j) * 64);
  wait4();                                       // old prefetch (older 4) done; anew stays in flight
#pragma unroll
  for (int j = 0; j < 4; ++j)
    *(int4*)(G + (4 + j) * 4096 + row * 128 + lj * 16) = P.v[j];
  bar_lds();                                     // old half staged

  f32x4 acc0 = {0.f, 0.f, 0.f, 0.f}, acc1 = {0.f, 0.f, 0.f, 0.f};
  const unsigned short* wbr = Wb + (size_t)wrowi * sWb + fh * 8;
#pragma unroll
  for (int j = 0; j < 4; ++j) {                  // MFMA old half (hides anew latency)
#pragma unroll
    for (int kk = 0; kk < 2; ++kk) {
      short8 b0 = *(const short8*)(wbr + (grp * 4 + j) * 64 + kk * 32);
      int colb = kk * 64 + fh * 16;
      short8 a0 = *(const short8*)(G + (4 + j) * 4096 + fl * 128 + (colb ^ swz));
      short8 a1 = *(const short8*)(G + (4 + j) * 4096 + (16 + fl) * 128 + (colb ^ swz));
      acc0 = __builtin_amdgcn_mfma_f32_16x16x32_bf16(a0, b0, acc0, 0, 0, 0);
      acc1 = __builtin_amdgcn_mfma_f32_16x16x32_bf16(a1, b0, acc1, 0, 0, 0);
    }
  }
  drain_vm();                                    // anew landed (covered by old MFMA)
#pragma unroll
  for (int j = 0; j < 4; ++j)
    *(int4*)(G + j * 4096 + row * 128 + lj * 16) = anew[j];
  bar_lds();                                     // new half staged
  const unsigned short* war = Wa + (size_t)wrowi * sWa + fh * 8;
#pragma unroll
  for (int j = 0; j < 4; ++j) {
#pragma unroll
    for (int kk = 0; kk < 2; ++kk) {
      short8 b0 = *(const short8*)(war + (grp * 4 + j) * 64 + kk * 32);
      int colb = kk * 64 + fh * 16;
      short8 a0 = *(const short8*)(G + j * 4096 + fl * 128 + (colb ^ swz));
      short8 a1 = *(const short8*)(G + j * 4096 + (16 + fl) * 128 + (colb ^ swz));
      acc0 = __builtin_amdgcn_mfma_f32_16x16x32_bf16(a0, b0, acc0, 0, 0, 0);
      acc1 = __builtin_amdgcn_mfma_f32_16x16x32_bf16(a1, b0, acc1, 0, 0, 0);
    }
  }
  exchange_cell(acc0, acc1, bias, creg, Hout, smem, m0, n0, ntile, tid);
}

// gt-step L1: K=19 tiles, all prefetched (seq + old h1), contiguous grp split
__device__ __forceinline__ void lstm_gtl1(const Pre5& P,
    const unsigned short* __restrict__ Wih1p, const unsigned short* __restrict__ Whh1,
    const float* __restrict__ bias,
    float& creg, unsigned short* __restrict__ Hout,
    char* smem, int m0, int n0, int ntile, int tid)
{
  const int wave = tid >> 6, lane = tid & 63;
  const int grp = wave >> 2, gw = wave & 3;
  const int lrow = lane >> 3, lj = lane & 7;
  const int fl = lane & 15, fh = lane >> 4;
  const int row = gw * 8 + lrow;
  const int swz = (fl & 7) << 4;
  const int wrowi = n0 + gw * 16 + fl;
  const int kt0 = grp * 5;
  const int ktn = 4 + (grp < 3 ? 1 : 0);
  char* G = smem + grp * 32768;

#pragma unroll
  for (int i = 0; i < 5; ++i)
    if (i < ktn) *(int4*)(G + i * 4096 + row * 128 + lj * 16) = P.v[i];
  bar_lds();

  f32x4 acc0 = {0.f, 0.f, 0.f, 0.f}, acc1 = {0.f, 0.f, 0.f, 0.f};
#pragma unroll
  for (int i = 0; i < 5; ++i) {
    if (i < ktn) {
      int kt = kt0 + i;
      const unsigned short* wr = (kt < 3)
          ? Wih1p + (size_t)wrowi * 192 + kt * 64 + fh * 8
          : Whh1 + (size_t)wrowi * HH + (kt - 3) * 64 + fh * 8;
#pragma unroll
      for (int kk = 0; kk < 2; ++kk) {
        short8 b0 = *(const short8*)(wr + kk * 32);
        int colb = kk * 64 + fh * 16;
        short8 a0 = *(const short8*)(G + i * 4096 + fl * 128 + (colb ^ swz));
        short8 a1 = *(const short8*)(G + i * 4096 + (16 + fl) * 128 + (colb ^ swz));
        acc0 = __builtin_amdgcn_mfma_f32_16x16x32_bf16(a0, b0, acc0, 0, 0, 0);
        acc1 = __builtin_amdgcn_mfma_f32_16x16x32_bf16(a1, b0, acc1, 0, 0, 0);
      }
    }
  }
  exchange_cell(acc0, acc1, bias, creg, Hout, smem, m0, n0, ntile, tid);
}

// decoder out tile: group-local 32 rows x 16 cols, K=1024 split over 16 waves
__device__ __forceinline__ void dec_out(
    const unsigned short* __restrict__ H3in, const unsigned short* __restrict__ Wd,
    const float* __restrict__ bd, float* __restrict__ out,
    int t, char* smem, int d, int tid, int m0)
{
  const int wave = tid >> 6, lane = tid & 63;
  const int lrow = lane >> 3, lj = lane & 7;
  const int fl = lane & 15, fh = lane >> 4;
  const int n0 = d * 16;
  char* Dr = smem + 65536 + wave * 4096;
  int4 r4[4];
#pragma unroll
  for (int j = 0; j < 4; ++j) {
    int row = j * 8 + lrow;
    r4[j] = ld_coh16(H3in + (size_t)(m0 + row) * HH + wave * 64 + ((lj ^ (row & 7)) << 3));
  }
  drain_vm();
#pragma unroll
  for (int j = 0; j < 4; ++j) {
    int row = j * 8 + lrow;
    *(int4*)(Dr + row * 128 + lj * 16) = r4[j];
  }
  f32x4 acc0 = {0.f, 0.f, 0.f, 0.f}, acc1 = {0.f, 0.f, 0.f, 0.f};
  const unsigned short* Wrow = Wd + (size_t)(n0 + fl) * HH + wave * 64 + fh * 8;
  const int swz = (fl & 7) << 4;
#pragma unroll
  for (int kk = 0; kk < 2; ++kk) {
    short8 b0 = *(const short8*)(Wrow + kk * 32);
    int colb = kk * 64 + fh * 16;
    short8 a0 = *(const short8*)(Dr + fl * 128 + (colb ^ swz));
    short8 a1 = *(const short8*)(Dr + (16 + fl) * 128 + (colb ^ swz));
    acc0 = __builtin_amdgcn_mfma_f32_16x16x32_bf16(a0, b0, acc0, 0, 0, 0);
    acc1 = __builtin_amdgcn_mfma_f32_16x16x32_bf16(a1, b0, acc1, 0, 0, 0);
  }
  float* pex = (float*)(smem + 32768);
#pragma unroll
  for (int r = 0; r < 4; ++r) {
    pex[(wave * 32 + fh * 4 + r) * 16 + fl] = acc0[r];
    pex[(wave * 32 + 16 + fh * 4 + r) * 16 + fl] = acc1[r];
  }
  bar_lds();
  if (tid < 512) {
    int rrow = tid >> 4, uu = tid & 15;
    int c = n0 + uu;
    if (c < CC) {
      float s = 0.f;
#pragma unroll
      for (int v = 0; v < 16; ++v) s += pex[(v * 32 + rrow) * 16 + uu];
      out[(size_t)(m0 + rrow) * (TT * CC) + (size_t)t * CC + c] = s + bd[c];
    }
  }
}

// ---------------- persistent megakernel ----------------
__global__ __launch_bounds__(1024, 4) void persistent_lstm(
    const unsigned short* __restrict__ Wih1p, const unsigned short* __restrict__ Whh1,
    const unsigned short* __restrict__ Wf, const unsigned short* __restrict__ W2,
    const unsigned short* __restrict__ W3, const unsigned short* __restrict__ Wd,
    const float* __restrict__ B1gt, const float* __restrict__ B1sc,
    const float* __restrict__ B2, const float* __restrict__ B3, const float* __restrict__ Bd,
    unsigned short* __restrict__ Hb, const float* __restrict__ seq, float* __restrict__ out,
    const int* __restrict__ gtp, const int* __restrict__ condp, int* __restrict__ bar)
{
  __shared__ char smem[131072];
  const int wg = blockIdx.x, tid = threadIdx.x;
  const int xg = wg & 7, sl = wg >> 3;
  const int ntile = xg * 8 + (sl >> 2);
  const int mgrp = sl & 3;
  const int m0 = mgrp * 32;
  const int n0 = ntile * 64;
  const int gt = *gtp, cond = *condp;
  const int per = gt + cond;
  const int lane = tid & 63, wave = tid >> 6;
  const int grp = wave >> 2, gw = wave & 3;
  const int lrow = lane >> 3, lj = lane & 7;
  const int row = gw * 8 + lrow;

  int dd = ((ntile & 7) << 3) | (ntile >> 3);    // bit-swap: spreads dec jobs over XCDs
  const int decid = (dd < 11) ? dd : -1;

  unsigned short* H1[2] = { Hb + 0 * BB * HH, Hb + 1 * BB * HH };
  unsigned short* H2[2] = { Hb + 2 * BB * HH, Hb + 3 * BB * HH };
  unsigned short* H3[2] = { Hb + 4 * BB * HH, Hb + 5 * BB * HH };
  int* B = bar + mgrp * 256;

  float c1 = 0.f, c2 = 0.f, c3 = 0.f;
  Pre4 aold; Pre5 a1pre;
  int e = 0, tm = 0;
  bool gts = (per > 0) ? (0 < gt) : true;
  if (gts) prefetch_gtl1(seq, H1[0], m0, grp, row, lj, a1pre);
  else     prefetch_old(H1[0], HH, m0, grp, row, lj, aold);

  for (int t = 0; t < TT; ++t) {
    int p = t & 1;
    // ---- L1 ----
    if (gts) lstm_gtl1(a1pre, Wih1p, Whh1, B1gt, c1, H1[1 - p], smem, m0, n0, ntile, tid);
    else     lstm_split(H3[p], HH, Wf, HH, Whh1, HH, B1sc, c1, H1[1 - p],
                        smem, m0, n0, ntile, tid, aold);
    if (decid >= 0 && t > 0) dec_out(H3[p], Wd, Bd, out, t - 1, smem, decid, tid, m0);
    prefetch_old(H2[p], HH, m0, grp, row, lj, aold);     // L2 old half
    wait4();
    groupbar(B, tid, ++e);
    // ---- L2 ----
    lstm_split(H1[1 - p], HH, W2, 2048, W2 + 1024, 2048, B2, c2, H2[1 - p],
               smem, m0, n0, ntile, tid, aold);
    prefetch_old(H3[p], HH, m0, grp, row, lj, aold);     // L3 old half
    wait4();
    groupbar(B, tid, ++e);
    // ---- L3 ----
    lstm_split(H2[1 - p], HH, W3, 2048, W3 + 1024, 2048, B3, c3, H3[1 - p],
               smem, m0, n0, ntile, tid, aold);
    // prefetch next step's L1
    int tmn = (tm + 1 == per) ? 0 : tm + 1;
    bool gtsn = (per > 0) ? (tmn < gt) : true;
    if (t + 1 < TT) {
      if (gtsn) prefetch_gtl1(seq + (size_t)(t + 1) * CC, H1[1 - p], m0, grp, row, lj, a1pre);
      else { prefetch_old(H1[1 - p], HH, m0, grp, row, lj, aold); wait4(); }
    } else drain_vm();
    groupbar(B, tid, ++e);
    tm = tmn; gts = gtsn;
  }
  if (decid >= 0) dec_out(H3[0], Wd, Bd, out, TT - 1, smem, decid, tid, m0);
}

// ---------------- conversion / init kernels ----------------
__device__ __forceinline__ int perm_orig_row(int np) {
  return ((np >> 4) & 3) * HH + ((np >> 6) << 4) + (np & 15);
}

__global__ void conv_wih1p(const float* __restrict__ Wih, unsigned short* __restrict__ dst) {
  int np = blockIdx.x, k = threadIdx.x;          // block 192
  int n = perm_orig_row(np);
  dst[(size_t)np * 192 + k] = f2bf((k < CC) ? Wih[(size_t)n * CC + k] : 0.f);
}

__global__ void conv_whh1(const float* __restrict__ Whh, unsigned short* __restrict__ dst) {
  int np = blockIdx.y, k = blockIdx.x * 256 + threadIdx.x;   // grid (4, 4096)
  int n = perm_orig_row(np);
  dst[(size_t)np * HH + k] = f2bf(Whh[(size_t)n * HH + k]);
}

__global__ void conv_w23(const float* __restrict__ Wih, const float* __restrict__ Whh,
                         unsigned short* __restrict__ dst) {
  int k = blockIdx.x * 256 + threadIdx.x;        // grid (8, 4096)
  int np = blockIdx.y;
  int n = perm_orig_row(np);
  float v = (k < HH) ? Wih[(size_t)n * HH + k] : Whh[(size_t)n * HH + (k - HH)];
  dst[(size_t)np * 2048 + k] = f2bf(v);
}

__global__ void conv_wd(const float* __restrict__ Wsrc, unsigned short* __restrict__ dst) {
  int k = blockIdx.x * 256 + threadIdx.x;        // grid (4, 176)
  int row = blockIdx.y;
  dst[(size_t)row * HH + k] = f2bf((row < CC) ? Wsrc[(size_t)row * HH + k] : 0.f);
}

__global__ void wf_gemm(const float* __restrict__ Wih1, const float* __restrict__ Wdec,
                        unsigned short* __restrict__ Wfo) {
  int j = blockIdx.x * 256 + threadIdx.x;        // grid (4, 4096)
  int np = blockIdx.y;
  int n = perm_orig_row(np);
  const float* wr = Wih1 + (size_t)n * CC;
  float acc = 0.f;
  for (int c = 0; c < CC; ++c) acc = fmaf(wr[c], Wdec[(size_t)c * HH + j], acc);
  Wfo[(size_t)np * HH + j] = f2bf(acc);
}

__global__ void bias_all(const float* bi1, const float* bh1, const float* Wih1, const float* bdec,
                         const float* bi2, const float* bh2, const float* bi3, const float* bh3,
                         float* o1gt, float* o1sc, float* o2, float* o3, float* od) {
  int idx = blockIdx.x * 256 + threadIdx.x;
  if (idx < 4096) {
    int n = perm_orig_row(idx);
    float b = bi1[n] + bh1[n];
    o1gt[idx] = b;
    const float* wr = Wih1 + (size_t)n * CC;
    float acc = 0.f;
    for (int c = 0; c < CC; ++c) acc = fmaf(wr[c], bdec[c], acc);
    o1sc[idx] = b + acc;
  } else if (idx < 8192) {
    int np = idx - 4096; int n = perm_orig_row(np);
    o2[np] = bi2[n] + bh2[n];
  } else if (idx < 12288) {
    int np = idx - 8192; int n = perm_orig_row(np);
    o3[np] = bi3[n] + bh3[n];
  } else if (idx < 12464) {
    int c2 = idx - 12288;
    od[c2] = (c2 < CC) ? bdec[c2] : 0.f;
  }
}

__global__ void init_state(unsigned short* __restrict__ Hall, int* __restrict__ bar) {
  int idx = blockIdx.x * blockDim.x + threadIdx.x;   // grid 3072 x 256
  if (idx < 6 * BB * HH) Hall[idx] = 0;
  if (idx < 1024) bar[idx] = 0;
}

extern "C" void kernel_launch(void* const* d_in, const int* in_sizes, int n_in,
                              void* d_out, int out_size, void* d_ws, size_t ws_size,
                              hipStream_t stream)
{
  const float* seq   = (const float*)d_in[0];
  const float* W_ih1 = (const float*)d_in[1];
  const float* W_hh1 = (const float*)d_in[2];
  const float* b_ih1 = (const float*)d_in[3];
  const float* b_hh1 = (const float*)d_in[4];
  const float* W_ih2 = (const float*)d_in[5];
  const float* W_hh2 = (const float*)d_in[6];
  const float* b_ih2 = (const float*)d_in[7];
  const float* b_hh2 = (const float*)d_in[8];
  const float* W_ih3 = (const float*)d_in[9];
  const float* W_hh3 = (const float*)d_in[10];
  const float* b_ih3 = (const float*)d_in[11];
  const float* b_hh3 = (const float*)d_in[12];
  const float* W_dec = (const float*)d_in[13];
  const float* b_dec = (const float*)d_in[14];
  const int* condp   = (const int*)d_in[15];
  const int* gtp     = (const int*)d_in[16];
  float* out = (float*)d_out;
  char* ws = (char*)d_ws;

  if (ws_size < 53908480) return;

  unsigned short* Wih1p = (unsigned short*)(ws + 0);
  unsigned short* Whh1  = (unsigned short*)(ws + 1572864);
  unsigned short* Wf    = (unsigned short*)(ws + 9961472);
  unsigned short* W2    = (unsigned short*)(ws + 18350080);
  unsigned short* W3    = (unsigned short*)(ws + 35127296);
  unsigned short* Wd    = (unsigned short*)(ws + 51904512);
  float* B1gt = (float*)(ws + 52264960);
  float* B1sc = (float*)(ws + 52281344);
  float* B2   = (float*)(ws + 52297728);
  float* B3   = (float*)(ws + 52314112);
  float* Bd   = (float*)(ws + 52330496);
  unsigned short* Hbase = (unsigned short*)(ws + 52331520);
  int* bar = (int*)(ws + 53904384);

  conv_wih1p<<<dim3(4096),    192, 0, stream>>>(W_ih1, Wih1p);
  conv_whh1 <<<dim3(4, 4096), 256, 0, stream>>>(W_hh1, Whh1);
  wf_gemm   <<<dim3(4, 4096), 256, 0, stream>>>(W_ih1, W_dec, Wf);
  conv_w23  <<<dim3(8, 4096), 256, 0, stream>>>(W_ih2, W_hh2, W2);
  conv_w23  <<<dim3(8, 4096), 256, 0, stream>>>(W_ih3, W_hh3, W3);
  conv_wd   <<<dim3(4, 176),  256, 0, stream>>>(W_dec, Wd);
  bias_all  <<<dim3(49),      256, 0, stream>>>(b_ih1, b_hh1, W_ih1, b_dec,
                                                b_ih2, b_hh2, b_ih3, b_hh3,
                                                B1gt, B1sc, B2, B3, Bd);
  init_state<<<dim3(3072),    256, 0, stream>>>(Hbase, bar);

  persistent_lstm<<<dim3(256), dim3(1024), 0, stream>>>(
      Wih1p, Whh1, Wf, W2, W3, Wd, B1gt, B1sc, B2, B3, Bd,
      Hbase, seq, out, gtp, condp, bar);
}